// Round 9
// baseline (382.112 us; speedup 1.0000x reference)
//
#include <hip/hip_runtime.h>
#include <stdint.h>

typedef unsigned short u16;
typedef __attribute__((ext_vector_type(8))) __bf16 bf16x8;
typedef __attribute__((ext_vector_type(4))) float f32x4;

__device__ __forceinline__ u16 f2bf(float f) {
    union { float f; uint32_t u; } v; v.f = f;
    uint32_t r = (v.u + 0x7FFFu + ((v.u >> 16) & 1u)) >> 16;
    return (u16)r;
}

// Wave-local LDS drain (WAR protection when a window is rewritten).
__device__ __forceinline__ void lds_fence() {
    __asm__ volatile("s_waitcnt lgkmcnt(0)" ::: "memory");
}

#define BM 128
#define BN 128
#define BK 64

// C = A * Bt^T, A [M,K] bf16 rm, Bt [N,K] bf16 rm. K % 128 == 0 (nIt even).
// K-loop (1 barrier per BK=64 iter):
//   - A double-buffered in LDS via global_load_lds (16 KB/buf)
//   - B direct global->VGPR in MFMA fragment layout, PREFETCHED ONE ITERATION
//     AHEAD into ping-pong register buffers (b0/b1). Loads issue right after
//     the barrier of iter kk and are consumed after the barrier of iter kk+1 —
//     a full compute phase of latency cover; the barrier's implicit vmcnt(0)
//     is the drain point (round-8 failure mode: same loads, zero cover).
// MODE 0: fused QKV projection, N=3072. Section bn>>10: 0->q(b0,o0), 1->k(b1,o1),
//         2->v(b2) TRANSPOSED [b,e,s] into o2.
// MODE 2: exp(s*scale) bf16 into o0 + atomic per-row sums into lsum.
// MODE 3: fp32 out = acc / lsum[row] into o3.
template<int MODE>
__global__ __launch_bounds__(256, 3) void gemm_bt(
    const u16* __restrict__ A, const u16* __restrict__ Bt,
    const float* __restrict__ b0b, const float* __restrict__ b1b, const float* __restrict__ b2b,
    u16* __restrict__ o0, u16* __restrict__ o1, u16* __restrict__ o2,
    float* __restrict__ o3, float* __restrict__ lsum,
    int M, int N, int K, long sA, long sB, long sC, float scale)
{
    __shared__ __align__(16) u16 smem[4 * 64 * 72]; // 36864 B
    // A staging: buf d (kk&1) at u16 offset d*8192, half h at +h*4096 ([128][32]).
    // Epilogue: per-wave 9216 B windows overlay (after final __syncthreads).

    const int t = threadIdx.x;
    const int lane = t & 63;
    const int wave = t >> 6;
    const int wm = (wave & 1) * 64;
    const int wn = (wave >> 1) * 64;
    const int bm = blockIdx.y * BM;
    const int bn = blockIdx.x * BN;
    const long bz = blockIdx.z;
    const u16* Ab = A + bz * sA;
    const u16* Bb = Bt + bz * sB;

    f32x4 acc[4][4];
#pragma unroll
    for (int i = 0; i < 4; ++i)
#pragma unroll
        for (int j = 0; j < 4; ++j)
            acc[i][j] = (f32x4){0.f, 0.f, 0.f, 0.f};

    const int lrow = t >> 2;          // 0..63
    const int lcol = (t & 3) * 8;     // 0,8,16,24 within a 32-col half
    const int fm = lane & 15;
    const int fk = (lane >> 4) * 8;

    // B fragment row pointers (one per j-tile)
    const u16* Bl[4];
#pragma unroll
    for (int j = 0; j < 4; ++j) Bl[j] = Bb + (long)(bn + wn + j * 16 + fm) * K + fk;

    const int nIt = K >> 6; // even

    bf16x8 bA[2][4], bB[2][4]; // ping-pong B fragment buffers

#define STAGE_A(kk)                                                                        \
    {                                                                                      \
        const int d_ = ((kk) & 1) * 8192;                                                  \
        _Pragma("unroll")                                                                  \
        for (int h_ = 0; h_ < 2; ++h_)                                                     \
            _Pragma("unroll")                                                              \
            for (int r_ = 0; r_ < 2; ++r_) {                                               \
                const u16* ga_ = Ab + (long)(bm + r_ * 64 + lrow) * K                      \
                                 + ((kk) * 64 + h_ * 32 + lcol);                           \
                __builtin_amdgcn_global_load_lds(                                          \
                    (const __attribute__((address_space(1))) void*)ga_,                    \
                    (__attribute__((address_space(3))) void*)&smem[d_ + h_ * 4096          \
                                                                  + (r_ * 256 + t) * 8],   \
                    16, 0, 0);                                                             \
            }                                                                              \
    }

#define LOAD_B(dst, kk)                                                                    \
    _Pragma("unroll")                                                                      \
    for (int h_ = 0; h_ < 2; ++h_)                                                         \
        _Pragma("unroll")                                                                  \
        for (int j_ = 0; j_ < 4; ++j_)                                                     \
            dst[h_][j_] = *(const bf16x8*)(Bl[j_] + (long)(kk) * 64 + h_ * 32);

#define COMPUTE(d_, bb)                                                                    \
    _Pragma("unroll")                                                                      \
    for (int h_ = 0; h_ < 2; ++h_) {                                                       \
        bf16x8 af_[4];                                                                     \
        _Pragma("unroll")                                                                  \
        for (int i_ = 0; i_ < 4; ++i_)                                                     \
            af_[i_] = *(const bf16x8*)&smem[(d_) + h_ * 4096 + (wm + i_ * 16 + fm) * 32 + fk]; \
        _Pragma("unroll")                                                                  \
        for (int i_ = 0; i_ < 4; ++i_)                                                     \
            _Pragma("unroll")                                                              \
            for (int j_ = 0; j_ < 4; ++j_)                                                 \
                acc[i_][j_] = __builtin_amdgcn_mfma_f32_16x16x32_bf16(af_[i_], bb[h_][j_], \
                                                                     acc[i_][j_], 0, 0, 0); \
    }

    STAGE_A(0);
    LOAD_B(bA, 0);
    for (int kk = 0; kk < nIt; kk += 2) {
        __syncthreads();                 // A(kk) DMA + bA regs drained; prior reads done
        STAGE_A(kk + 1);
        LOAD_B(bB, kk + 1);
        COMPUTE(0, bA);
        __syncthreads();                 // A(kk+1) DMA + bB regs drained; buf0 reads done
        if (kk + 2 < nIt) {
            STAGE_A(kk + 2);
            LOAD_B(bA, kk + 2);
        }
        COMPUTE(8192, bB);
    }
    __syncthreads(); // drain last staging reads before epilogue overlays the buffers

#undef STAGE_A
#undef LOAD_B
#undef COMPUTE

    // C/D layout: col = lane&15, row = (lane>>4)*4 + reg
    const int cm = (lane >> 4) * 4;
    const int cn = lane & 15;
    u16* Ew = smem + wave * 4608; // 9216 B per-wave window

    if (MODE == 3) {
        // ---- fp32 out (PV), /lsum[row]: 2 passes of 32 rows, stride 68 fp32 ----
        float* Fw = (float*)Ew; // 32*68*4 = 8704 B <= 9216
#pragma unroll
        for (int p = 0; p < 2; ++p) {
            if (p) lds_fence();
#pragma unroll
            for (int ii = 0; ii < 2; ++ii) {
                const int i = p * 2 + ii;
#pragma unroll
                for (int j = 0; j < 4; ++j)
#pragma unroll
                    for (int r = 0; r < 4; ++r)
                        Fw[(ii * 16 + cm + r) * 68 + j * 16 + cn] = acc[i][j][r];
            }
#pragma unroll
            for (int it = 0; it < 8; ++it) {
                const int row = it * 4 + (lane >> 4);
                const int c4 = (lane & 15) * 4;
                f32x4 w = *(const f32x4*)&Fw[row * 68 + c4];
                const int gm = bm + wm + p * 32 + row;
                const float inv = __builtin_amdgcn_rcpf(lsum[bz * 2048 + gm]);
                w[0] *= inv; w[1] *= inv; w[2] *= inv; w[3] *= inv;
                *(f32x4*)&o3[bz * sC + (long)gm * N + bn + wn + c4] = w;
            }
        }
    } else if (MODE == 0 && (bn >> 10) == 2) {
        // ---- v projection: transposed [b,e,s]; single-shot ----
        float bb[4];
#pragma unroll
        for (int j = 0; j < 4; ++j) bb[j] = b2b[(bn & 1023) + wn + j * 16 + cn];
        const int bgi = (bm + wm) >> 11;
        const int sbase = (bm + wm) & 2047;
#pragma unroll
        for (int i = 0; i < 4; ++i)
#pragma unroll
            for (int j = 0; j < 4; ++j) {
                ushort4 pk;
                pk.x = f2bf(acc[i][j][0] + bb[j]);
                pk.y = f2bf(acc[i][j][1] + bb[j]);
                pk.z = f2bf(acc[i][j][2] + bb[j]);
                pk.w = f2bf(acc[i][j][3] + bb[j]);
                *(ushort4*)&Ew[(j * 16 + cn) * 72 + i * 16 + cm] = pk; // [e][s]
            }
#pragma unroll
        for (int it = 0; it < 8; ++it) {
            const int e = it * 8 + (lane >> 3);
            const int s8 = (lane & 7) * 8;
            const uint4 w = *(const uint4*)&Ew[e * 72 + s8];
            const int eg = (bn & 1023) + wn + e;
            *(uint4*)&o2[((((long)bgi << 10) + eg) << 11) + sbase + s8] = w;
        }
    } else if (MODE == 0) {
        // ---- q/k projection, row-major bf16, single-shot ----
        const int sec = bn >> 10;
        u16* C = sec ? o1 : o0;
        const float* bias = sec ? b1b : b0b;
        const int ncol0 = bn & 1023;
        float bb[4];
#pragma unroll
        for (int j = 0; j < 4; ++j) bb[j] = bias[ncol0 + wn + j * 16 + cn];
#pragma unroll
        for (int i = 0; i < 4; ++i)
#pragma unroll
            for (int j = 0; j < 4; ++j) {
                const int col = j * 16 + cn;
#pragma unroll
                for (int r = 0; r < 4; ++r)
                    Ew[(i * 16 + cm + r) * 72 + col] = f2bf(acc[i][j][r] + bb[j]);
            }
#pragma unroll
        for (int it = 0; it < 8; ++it) {
            const int row = it * 8 + (lane >> 3);
            const int c8 = (lane & 7) * 8;
            const uint4 w = *(const uint4*)&Ew[row * 72 + c8];
            const int gm = bm + wm + row;
            *(uint4*)&C[(long)gm * 1024 + ncol0 + wn + c8] = w;
        }
    } else {
        // ---- MODE 2: exp(s*scale), row-sum atomics, single-shot bf16 retile ----
#pragma unroll
        for (int i = 0; i < 4; ++i)
#pragma unroll
            for (int j = 0; j < 4; ++j)
#pragma unroll
                for (int r = 0; r < 4; ++r)
                    acc[i][j][r] = __expf(acc[i][j][r] * scale);
#pragma unroll
        for (int i = 0; i < 4; ++i) {
#pragma unroll
            for (int r = 0; r < 4; ++r) {
                float s = acc[i][0][r] + acc[i][1][r] + acc[i][2][r] + acc[i][3][r];
                s += __shfl_xor(s, 1);
                s += __shfl_xor(s, 2);
                s += __shfl_xor(s, 4);
                s += __shfl_xor(s, 8);
                if (cn == 0)
                    atomicAdd(&lsum[bz * 2048 + bm + wm + i * 16 + cm + r], s);
            }
        }
#pragma unroll
        for (int i = 0; i < 4; ++i)
#pragma unroll
            for (int j = 0; j < 4; ++j) {
                const int col = j * 16 + cn;
#pragma unroll
                for (int r = 0; r < 4; ++r)
                    Ew[(i * 16 + cm + r) * 72 + col] = f2bf(acc[i][j][r]);
            }
#pragma unroll
        for (int it = 0; it < 8; ++it) {
            const int row = it * 8 + (lane >> 3);
            const int c8 = (lane & 7) * 8;
            const uint4 w = *(const uint4*)&Ew[row * 72 + c8];
            const int gm = bm + wm + row;
            *(uint4*)&o0[bz * sC + (long)gm * N + bn + wn + c8] = w;
        }
    }
}

// fp32 -> bf16 converts + lsum zeroing.
__global__ __launch_bounds__(256) void cvt_all(
    const float* __restrict__ x, const float* __restrict__ wq,
    const float* __restrict__ wk, const float* __restrict__ wv,
    u16* __restrict__ xb, u16* __restrict__ wb, float* __restrict__ lsum)
{
    const int b = blockIdx.x;
    if (b >= 11264) {
        const long i = (long)(b - 11264) * 1024 + threadIdx.x * 4;
        *(f32x4*)(lsum + i) = (f32x4){0.f, 0.f, 0.f, 0.f};
        return;
    }
    const float* src; u16* dst; long base;
    if (b < 8192)       { src = x;  dst = xb;             base = (long)b * 1024; }
    else if (b < 9216)  { src = wq; dst = wb;             base = (long)(b - 8192) * 1024; }
    else if (b < 10240) { src = wk; dst = wb + (1 << 20); base = (long)(b - 9216) * 1024; }
    else                { src = wv; dst = wb + (2 << 20); base = (long)(b - 10240) * 1024; }
    const long i = base + threadIdx.x * 4;
    const f32x4 f = *(const f32x4*)(src + i);
    ushort4 o;
    o.x = f2bf(f[0]); o.y = f2bf(f[1]); o.z = f2bf(f[2]); o.w = f2bf(f[3]);
    *(ushort4*)(dst + i) = o;
}

extern "C" void kernel_launch(void* const* d_in, const int* in_sizes, int n_in,
                              void* d_out, int out_size, void* d_ws, size_t ws_size,
                              hipStream_t stream) {
    const float* x  = (const float*)d_in[0];
    const float* Wq = (const float*)d_in[1];
    const float* bq = (const float*)d_in[2];
    const float* Wk = (const float*)d_in[3];
    const float* bk = (const float*)d_in[4];
    const float* Wv = (const float*)d_in[5];
    const float* bv = (const float*)d_in[6];
    float* out = (float*)d_out;

    const int B = 4, S = 2048, D = 1024, E = 1024;
    const int M = B * S; // 8192

    u16* xb  = (u16*)d_ws;                       // [M,D]
    u16* wb  = xb  + (size_t)M * D;              // [3E,D]
    u16* qb  = wb  + (size_t)3 * E * D;          // [M,E]
    u16* kb  = qb  + (size_t)M * E;              // [M,E]
    u16* vbT = kb  + (size_t)M * E;              // [B,E,S]
    u16* sb  = vbT + (size_t)M * E;              // [B,S,S] exp-scores
    float* lsum = (float*)(sb + (size_t)M * S);  // [M]

    cvt_all<<<11272, 256, 0, stream>>>(x, Wq, Wk, Wv, xb, wb, lsum);

    dim3 blk(256);
    gemm_bt<0><<<dim3(3 * E / BN, M / BM, 1), blk, 0, stream>>>(
        xb, wb, bq, bk, bv, qb, kb, vbT, nullptr, nullptr, M, 3 * E, D, 0, 0, 0, 1.f);
    gemm_bt<2><<<dim3(S / BN, S / BM, B), blk, 0, stream>>>(
        qb, kb, nullptr, nullptr, nullptr, sb, nullptr, nullptr, nullptr, lsum,
        S, S, E, (long)S * E, (long)S * E, (long)S * S, 0.03125f);
    gemm_bt<3><<<dim3(E / BN, S / BM, B), blk, 0, stream>>>(
        sb, vbT, nullptr, nullptr, nullptr, nullptr, nullptr, nullptr, out, lsum,
        S, E, S, (long)S * S, (long)E * S, (long)S * E, 1.f);
}

// Round 10
// 232.274 us; speedup vs baseline: 1.6451x; 1.6451x over previous
//
#include <hip/hip_runtime.h>
#include <stdint.h>

typedef unsigned short u16;
typedef __attribute__((ext_vector_type(8))) __bf16 bf16x8;
typedef __attribute__((ext_vector_type(4))) float f32x4;

__device__ __forceinline__ u16 f2bf(float f) {
    union { float f; uint32_t u; } v; v.f = f;
    uint32_t r = (v.u + 0x7FFFu + ((v.u >> 16) & 1u)) >> 16;
    return (u16)r;
}

// Wave-local LDS drain (WAR protection when a window is rewritten).
__device__ __forceinline__ void lds_fence() {
    __asm__ volatile("s_waitcnt lgkmcnt(0)" ::: "memory");
}

#define BM 128
#define BN 128
#define BK 64   // staged as two [128][32] halves (round-7 structure, best measured)

// C = A * Bt^T, A [M,K] bf16 rm, Bt [N,K] bf16 rm. K % 64 == 0.
// Round-7 K-loop (both operands staged, 2 barriers / BK=64) + XCD-aware 1-D grid
// swizzle: xcd = id%8 (HW round-robin); each XCD gets a clustered (z, bm-band)
// region so its ~64-96 resident blocks share operand strips inside the 4 MB L2.
// MODE 0: fused QKV projection, N=3072, grid 1536. Section bn>>10: 0->q(b0,o0),
//         1->k(b1,o1), 2->v(b2) TRANSPOSED [b,e,s] into o2.
// MODE 2: exp(s*scale) bf16 into o0 + atomic row sums into lsum. grid 1024.
// MODE 3: fp32 out = acc / lsum[row] into o3. grid 512.
template<int MODE>
__global__ __launch_bounds__(256, 4) void gemm_bt(
    const u16* __restrict__ A, const u16* __restrict__ Bt,
    const float* __restrict__ b0, const float* __restrict__ b1, const float* __restrict__ b2,
    u16* __restrict__ o0, u16* __restrict__ o1, u16* __restrict__ o2,
    float* __restrict__ o3, float* __restrict__ lsum,
    int M, int N, int K, long sA, long sB, long sC, float scale)
{
    __shared__ __align__(16) u16 smem[4 * 64 * 72]; // 36864 B
    // staging: A half0 @0, A half1 @4096, B half0 @8192, B half1 @12288 (u16 idx)

    const int t = threadIdx.x;
    const int lane = t & 63;
    const int wave = t >> 6;
    const int wm = (wave & 1) * 64;
    const int wn = (wave >> 1) * 64;

    // ---- XCD-aware block swizzle ----
    const int id = blockIdx.x;
    const int xcd = id & 7;
    const int s = id >> 3;
    int bm, bn;
    long bz;
    if (MODE == 0) {        // 1536 blocks: 24 bn x 64 bm; XCD k -> bm band [8k, 8k+8)
        bn = (s >> 3) * BN;
        bm = (xcd * 8 + (s & 7)) * BM;
        bz = 0;
    } else if (MODE == 2) { // 1024 blocks: 16 bn x 16 bm x 4 z; XCD -> (z, bm half)
        bz = xcd >> 1;
        bn = (s & 15) * BN;
        bm = ((xcd & 1) * 8 + (s >> 4)) * BM;
    } else {                // 512 blocks: 8 bn x 16 bm x 4 z; XCD -> (z, bm half)
        bz = xcd >> 1;
        bn = (s & 7) * BN;
        bm = ((xcd & 1) * 8 + (s >> 3)) * BM;
    }

    const u16* Ab = A + bz * sA;
    const u16* Bb = Bt + bz * sB;

    f32x4 acc[4][4];
#pragma unroll
    for (int i = 0; i < 4; ++i)
#pragma unroll
        for (int j = 0; j < 4; ++j)
            acc[i][j] = (f32x4){0.f, 0.f, 0.f, 0.f};

    const int lrow = t >> 2;          // 0..63
    const int lcol = (t & 3) * 8;     // 0,8,16,24 within a 32-col half
    const int fm = lane & 15;
    const int fk = (lane >> 4) * 8;

    for (int k0 = 0; k0 < K; k0 += BK) {
#pragma unroll
        for (int h = 0; h < 2; ++h)
#pragma unroll
            for (int r = 0; r < 2; ++r) {
                const u16* ga = Ab + (long)(bm + r * 64 + lrow) * K + (k0 + h * 32 + lcol);
                __builtin_amdgcn_global_load_lds(
                    (const __attribute__((address_space(1))) void*)ga,
                    (__attribute__((address_space(3))) void*)&smem[h * 4096 + (r * 256 + t) * 8],
                    16, 0, 0);
            }
#pragma unroll
        for (int h = 0; h < 2; ++h)
#pragma unroll
            for (int r = 0; r < 2; ++r) {
                const u16* gb = Bb + (long)(bn + r * 64 + lrow) * K + (k0 + h * 32 + lcol);
                __builtin_amdgcn_global_load_lds(
                    (const __attribute__((address_space(1))) void*)gb,
                    (__attribute__((address_space(3))) void*)&smem[8192 + h * 4096 + (r * 256 + t) * 8],
                    16, 0, 0);
            }
        __syncthreads();

#pragma unroll
        for (int h = 0; h < 2; ++h) {
            bf16x8 af[4], bfr[4];
#pragma unroll
            for (int i = 0; i < 4; ++i) {
                af[i]  = *(const bf16x8*)&smem[h * 4096 + (wm + i * 16 + fm) * 32 + fk];
                bfr[i] = *(const bf16x8*)&smem[8192 + h * 4096 + (wn + i * 16 + fm) * 32 + fk];
            }
#pragma unroll
            for (int i = 0; i < 4; ++i)
#pragma unroll
                for (int j = 0; j < 4; ++j)
                    acc[i][j] = __builtin_amdgcn_mfma_f32_16x16x32_bf16(af[i], bfr[j], acc[i][j], 0, 0, 0);
        }
        __syncthreads();
    }

    // C/D layout: col = lane&15, row = (lane>>4)*4 + reg
    const int cm = (lane >> 4) * 4;
    const int cn = lane & 15;
    u16* Ew = smem + wave * 4608; // 9216 B per-wave window

    if (MODE == 3) {
        // ---- fp32 out (PV), /lsum[row]: 2 passes of 32 rows, stride 68 fp32 ----
        float* Fw = (float*)Ew; // 32*68*4 = 8704 B <= 9216
#pragma unroll
        for (int p = 0; p < 2; ++p) {
            if (p) lds_fence();
#pragma unroll
            for (int ii = 0; ii < 2; ++ii) {
                const int i = p * 2 + ii;
#pragma unroll
                for (int j = 0; j < 4; ++j)
#pragma unroll
                    for (int r = 0; r < 4; ++r)
                        Fw[(ii * 16 + cm + r) * 68 + j * 16 + cn] = acc[i][j][r];
            }
#pragma unroll
            for (int it = 0; it < 8; ++it) {
                const int row = it * 4 + (lane >> 4);
                const int c4 = (lane & 15) * 4;
                f32x4 w = *(const f32x4*)&Fw[row * 68 + c4];
                const int gm = bm + wm + p * 32 + row;
                const float inv = __builtin_amdgcn_rcpf(lsum[bz * 2048 + gm]);
                w[0] *= inv; w[1] *= inv; w[2] *= inv; w[3] *= inv;
                *(f32x4*)&o3[bz * sC + (long)gm * N + bn + wn + c4] = w;
            }
        }
    } else if (MODE == 0 && (bn >> 10) == 2) {
        // ---- v projection: transposed [b,e,s]; single-shot ----
        float bb[4];
#pragma unroll
        for (int j = 0; j < 4; ++j) bb[j] = b2[(bn & 1023) + wn + j * 16 + cn];
        const int bgi = (bm + wm) >> 11;
        const int sbase = (bm + wm) & 2047;
#pragma unroll
        for (int i = 0; i < 4; ++i)
#pragma unroll
            for (int j = 0; j < 4; ++j) {
                ushort4 pk;
                pk.x = f2bf(acc[i][j][0] + bb[j]);
                pk.y = f2bf(acc[i][j][1] + bb[j]);
                pk.z = f2bf(acc[i][j][2] + bb[j]);
                pk.w = f2bf(acc[i][j][3] + bb[j]);
                *(ushort4*)&Ew[(j * 16 + cn) * 72 + i * 16 + cm] = pk; // [e][s]
            }
#pragma unroll
        for (int it = 0; it < 8; ++it) {
            const int e = it * 8 + (lane >> 3);
            const int s8 = (lane & 7) * 8;
            const uint4 w = *(const uint4*)&Ew[e * 72 + s8];
            const int eg = (bn & 1023) + wn + e;
            *(uint4*)&o2[((((long)bgi << 10) + eg) << 11) + sbase + s8] = w;
        }
    } else if (MODE == 0) {
        // ---- q/k projection, row-major bf16, single-shot ----
        const int sec = bn >> 10;
        u16* C = sec ? o1 : o0;
        const float* bias = sec ? b1 : b0;
        const int ncol0 = bn & 1023;
        float bb[4];
#pragma unroll
        for (int j = 0; j < 4; ++j) bb[j] = bias[ncol0 + wn + j * 16 + cn];
#pragma unroll
        for (int i = 0; i < 4; ++i)
#pragma unroll
            for (int j = 0; j < 4; ++j) {
                const int col = j * 16 + cn;
#pragma unroll
                for (int r = 0; r < 4; ++r)
                    Ew[(i * 16 + cm + r) * 72 + col] = f2bf(acc[i][j][r] + bb[j]);
            }
#pragma unroll
        for (int it = 0; it < 8; ++it) {
            const int row = it * 8 + (lane >> 3);
            const int c8 = (lane & 7) * 8;
            const uint4 w = *(const uint4*)&Ew[row * 72 + c8];
            const int gm = bm + wm + row;
            *(uint4*)&C[(long)gm * 1024 + ncol0 + wn + c8] = w;
        }
    } else {
        // ---- MODE 2: exp(s*scale), row-sum atomics, single-shot bf16 retile ----
#pragma unroll
        for (int i = 0; i < 4; ++i)
#pragma unroll
            for (int j = 0; j < 4; ++j)
#pragma unroll
                for (int r = 0; r < 4; ++r)
                    acc[i][j][r] = __expf(acc[i][j][r] * scale);
#pragma unroll
        for (int i = 0; i < 4; ++i) {
#pragma unroll
            for (int r = 0; r < 4; ++r) {
                float sm = acc[i][0][r] + acc[i][1][r] + acc[i][2][r] + acc[i][3][r];
                sm += __shfl_xor(sm, 1);
                sm += __shfl_xor(sm, 2);
                sm += __shfl_xor(sm, 4);
                sm += __shfl_xor(sm, 8);
                if (cn == 0)
                    atomicAdd(&lsum[bz * 2048 + bm + wm + i * 16 + cm + r], sm);
            }
        }
#pragma unroll
        for (int i = 0; i < 4; ++i)
#pragma unroll
            for (int j = 0; j < 4; ++j) {
                const int col = j * 16 + cn;
#pragma unroll
                for (int r = 0; r < 4; ++r)
                    Ew[(i * 16 + cm + r) * 72 + col] = f2bf(acc[i][j][r]);
            }
#pragma unroll
        for (int it = 0; it < 8; ++it) {
            const int row = it * 8 + (lane >> 3);
            const int c8 = (lane & 7) * 8;
            const uint4 w = *(const uint4*)&Ew[row * 72 + c8];
            const int gm = bm + wm + row;
            *(uint4*)&o0[bz * sC + (long)gm * N + bn + wn + c8] = w;
        }
    }
}

// fp32 -> bf16 converts + lsum zeroing.
__global__ __launch_bounds__(256) void cvt_all(
    const float* __restrict__ x, const float* __restrict__ wq,
    const float* __restrict__ wk, const float* __restrict__ wv,
    u16* __restrict__ xb, u16* __restrict__ wb, float* __restrict__ lsum)
{
    const int b = blockIdx.x;
    if (b >= 11264) {
        const long i = (long)(b - 11264) * 1024 + threadIdx.x * 4;
        *(f32x4*)(lsum + i) = (f32x4){0.f, 0.f, 0.f, 0.f};
        return;
    }
    const float* src; u16* dst; long base;
    if (b < 8192)       { src = x;  dst = xb;             base = (long)b * 1024; }
    else if (b < 9216)  { src = wq; dst = wb;             base = (long)(b - 8192) * 1024; }
    else if (b < 10240) { src = wk; dst = wb + (1 << 20); base = (long)(b - 9216) * 1024; }
    else                { src = wv; dst = wb + (2 << 20); base = (long)(b - 10240) * 1024; }
    const long i = base + threadIdx.x * 4;
    const f32x4 f = *(const f32x4*)(src + i);
    ushort4 o;
    o.x = f2bf(f[0]); o.y = f2bf(f[1]); o.z = f2bf(f[2]); o.w = f2bf(f[3]);
    *(ushort4*)(dst + i) = o;
}

extern "C" void kernel_launch(void* const* d_in, const int* in_sizes, int n_in,
                              void* d_out, int out_size, void* d_ws, size_t ws_size,
                              hipStream_t stream) {
    const float* x  = (const float*)d_in[0];
    const float* Wq = (const float*)d_in[1];
    const float* bq = (const float*)d_in[2];
    const float* Wk = (const float*)d_in[3];
    const float* bk = (const float*)d_in[4];
    const float* Wv = (const float*)d_in[5];
    const float* bv = (const float*)d_in[6];
    float* out = (float*)d_out;

    const int B = 4, S = 2048, D = 1024, E = 1024;
    const int M = B * S; // 8192

    u16* xb  = (u16*)d_ws;                       // [M,D]
    u16* wb  = xb  + (size_t)M * D;              // [3E,D]
    u16* qb  = wb  + (size_t)3 * E * D;          // [M,E]
    u16* kb  = qb  + (size_t)M * E;              // [M,E]
    u16* vbT = kb  + (size_t)M * E;              // [B,E,S]
    u16* sb  = vbT + (size_t)M * E;              // [B,S,S] exp-scores
    float* lsum = (float*)(sb + (size_t)M * S);  // [M]

    cvt_all<<<11272, 256, 0, stream>>>(x, Wq, Wk, Wv, xb, wb, lsum);

    dim3 blk(256);
    gemm_bt<0><<<1536, blk, 0, stream>>>(
        xb, wb, bq, bk, bv, qb, kb, vbT, nullptr, nullptr, M, 3 * E, D, 0, 0, 0, 1.f);
    gemm_bt<2><<<1024, blk, 0, stream>>>(
        qb, kb, nullptr, nullptr, nullptr, sb, nullptr, nullptr, nullptr, lsum,
        S, S, E, (long)S * E, (long)S * E, (long)S * S, 0.03125f);
    gemm_bt<3><<<512, blk, 0, stream>>>(
        sb, vbT, nullptr, nullptr, nullptr, nullptr, nullptr, nullptr, out, lsum,
        S, E, S, (long)S * S, (long)E * S, (long)S * E, 1.f);
}